// Round 1
// baseline (2597.564 us; speedup 1.0000x reference)
//
#include <hip/hip_runtime.h>
#include <hip/hip_bf16.h>
#include <math.h>

// ---------------------------------------------------------------------------
// GCN 4-layer: per layer  h = relu( A_w @ (h @ W) + b ), final log_softmax.
// Strategy:
//   1. Build dst-CSR once per call (histogram -> scan -> scatter src/ew).
//   2. Per layer: tiled fp32 GEMM (support = h @ W), then CSR SpMM with one
//      wave per dst node (register accumulate, no fp32 atomics), fusing
//      bias+relu into the SpMM epilogue.
//   3. log_softmax over 40 classes, one wave per row.
// ---------------------------------------------------------------------------

#define WAVE 64

// ---------------- CSR build ----------------

__global__ __launch_bounds__(256) void hist_kernel(const int* __restrict__ dst,
                                                   int nE, int* __restrict__ counts) {
    int i = blockIdx.x * 256 + threadIdx.x;
    if (i < nE) atomicAdd(&counts[dst[i]], 1);
}

// Block-wise Hillis-Steele scan: writes per-chunk exclusive scan + chunk totals.
__global__ __launch_bounds__(1024) void scan1_kernel(const int* __restrict__ counts,
                                                     int n, int* __restrict__ partial,
                                                     int* __restrict__ bsum) {
    __shared__ int sm[1024];
    int tid = threadIdx.x;
    int i = blockIdx.x * 1024 + tid;
    int x = (i < n) ? counts[i] : 0;
    sm[tid] = x;
    __syncthreads();
    for (int off = 1; off < 1024; off <<= 1) {
        int add = 0;
        if (tid >= off) add = sm[tid - off];
        __syncthreads();
        if (tid >= off) sm[tid] += add;
        __syncthreads();
    }
    int incl = sm[tid];
    if (i < n) partial[i] = incl - x;   // exclusive within chunk
    if (tid == 1023) bsum[blockIdx.x] = incl;
}

__global__ __launch_bounds__(1024) void scan2_kernel(const int* __restrict__ bsum,
                                                     int nb, int* __restrict__ boff) {
    __shared__ int sm[1024];
    int tid = threadIdx.x;
    int x = (tid < nb) ? bsum[tid] : 0;
    sm[tid] = x;
    __syncthreads();
    for (int off = 1; off < 1024; off <<= 1) {
        int add = 0;
        if (tid >= off) add = sm[tid - off];
        __syncthreads();
        if (tid >= off) sm[tid] += add;
        __syncthreads();
    }
    if (tid < nb) boff[tid] = sm[tid] - x;  // exclusive scan of block sums
}

__global__ __launch_bounds__(256) void scan3_kernel(int* __restrict__ row_ptr,
                                                    const int* __restrict__ boff,
                                                    int n, int nE,
                                                    int* __restrict__ row_cur) {
    int i = blockIdx.x * 256 + threadIdx.x;
    if (i < n) {
        int v = row_ptr[i] + boff[i >> 10];
        row_ptr[i] = v;
        row_cur[i] = v;
    }
    if (i == 0) row_ptr[n] = nE;
}

__global__ __launch_bounds__(256) void scatter_kernel(const int* __restrict__ src,
                                                      const int* __restrict__ dst,
                                                      const float* __restrict__ ew,
                                                      int nE,
                                                      int* __restrict__ row_cur,
                                                      int* __restrict__ src_s,
                                                      float* __restrict__ ew_s) {
    int i = blockIdx.x * 256 + threadIdx.x;
    if (i < nE) {
        int d = dst[i];
        int pos = atomicAdd(&row_cur[d], 1);
        src_s[pos] = src[i];
        ew_s[pos] = ew[i];
    }
}

// ---------------- GEMM: C[M,N] = A[M,K] @ W[K,N] (fp32, LDS-tiled) ----------

#define BM 64
#define BN 64
#define BKK 16

__global__ __launch_bounds__(256) void gemm_kernel(const float* __restrict__ A,
                                                   const float* __restrict__ W,
                                                   float* __restrict__ C,
                                                   int M, int K, int N) {
    __shared__ float As[BKK][BM];   // A transposed tile
    __shared__ float Bs[BKK][BN];
    const int t = threadIdx.x;           // 0..255
    const int tx = t & 15;               // N sub-tile
    const int ty = t >> 4;               // M sub-tile
    const int row0 = blockIdx.y * BM;
    const int col0 = blockIdx.x * BN;

    float acc[4][4];
#pragma unroll
    for (int i = 0; i < 4; i++)
#pragma unroll
        for (int j = 0; j < 4; j++) acc[i][j] = 0.f;

    for (int k0 = 0; k0 < K; k0 += BKK) {
        // Load A tile 64x16 (K is always a multiple of 16)
#pragma unroll
        for (int i = 0; i < 4; i++) {
            int idx = t + i * 256;
            int m = idx >> 4;
            int kk = idx & 15;
            int gm = row0 + m;
            float v = 0.f;
            if (gm < M) v = A[(size_t)gm * K + k0 + kk];
            As[kk][m] = v;
        }
        // Load B tile 16x64
#pragma unroll
        for (int i = 0; i < 4; i++) {
            int idx = t + i * 256;
            int kk = idx >> 6;
            int n = idx & 63;
            int gn = col0 + n;
            float v = 0.f;
            if (gn < N) v = W[(size_t)(k0 + kk) * N + gn];
            Bs[kk][n] = v;
        }
        __syncthreads();
#pragma unroll
        for (int kk = 0; kk < BKK; kk++) {
            float a[4], b[4];
#pragma unroll
            for (int i = 0; i < 4; i++) a[i] = As[kk][ty * 4 + i];
#pragma unroll
            for (int j = 0; j < 4; j++) b[j] = Bs[kk][tx * 4 + j];
#pragma unroll
            for (int i = 0; i < 4; i++)
#pragma unroll
                for (int j = 0; j < 4; j++) acc[i][j] += a[i] * b[j];
        }
        __syncthreads();
    }
#pragma unroll
    for (int i = 0; i < 4; i++) {
        int gm = row0 + ty * 4 + i;
        if (gm >= M) continue;
#pragma unroll
        for (int j = 0; j < 4; j++) {
            int gn = col0 + tx * 4 + j;
            if (gn < N) C[(size_t)gm * N + gn] = acc[i][j];
        }
    }
}

// ---------------- SpMM (CSR by dst) + bias + relu ---------------------------
// One wave per destination node; lane covers VEC contiguous columns.

template <int D, int VEC>
__global__ __launch_bounds__(256) void spmm_bias_relu(const int* __restrict__ row_ptr,
                                                      const int* __restrict__ src_s,
                                                      const float* __restrict__ ew_s,
                                                      const float* __restrict__ support,
                                                      const float* __restrict__ bias,
                                                      float* __restrict__ out,
                                                      int n_nodes) {
    int node = blockIdx.x * (256 / WAVE) + (threadIdx.x >> 6);
    int lane = threadIdx.x & 63;
    if (node >= n_nodes) return;
    int beg = row_ptr[node];
    int end = row_ptr[node + 1];
    int col = lane * VEC;
    if (col >= D) return;

    float acc[VEC];
#pragma unroll
    for (int i = 0; i < VEC; i++) acc[i] = 0.f;

    for (int e = beg; e < end; e++) {
        int s = src_s[e];
        float w = ew_s[e];
        const float* p = support + (size_t)s * D + col;
        if (VEC == 4) {
            float4 v = *(const float4*)p;
            acc[0] += v.x * w; acc[1] += v.y * w; acc[2] += v.z * w; acc[3] += v.w * w;
        } else if (VEC == 2) {
            float2 v = *(const float2*)p;
            acc[0] += v.x * w; acc[1] += v.y * w;
        } else {
            acc[0] += p[0] * w;
        }
    }
#pragma unroll
    for (int i = 0; i < VEC; i++) {
        float r = acc[i] + bias[col + i];
        out[(size_t)node * D + col + i] = r > 0.f ? r : 0.f;
    }
}

// ---------------- log_softmax over 40 classes, one wave per row -------------

__global__ __launch_bounds__(256) void logsoftmax40_kernel(const float* __restrict__ h,
                                                           float* __restrict__ out,
                                                           int n_nodes) {
    int row = blockIdx.x * (256 / WAVE) + (threadIdx.x >> 6);
    int lane = threadIdx.x & 63;
    if (row >= n_nodes) return;
    float v = (lane < 40) ? h[(size_t)row * 40 + lane] : -INFINITY;
    float m = v;
#pragma unroll
    for (int off = 32; off; off >>= 1) m = fmaxf(m, __shfl_xor(m, off));
    float e = (lane < 40) ? __expf(v - m) : 0.f;
    float s = e;
#pragma unroll
    for (int off = 32; off; off >>= 1) s += __shfl_xor(s, off);
    if (lane < 40) out[(size_t)row * 40 + lane] = v - m - __logf(s);
}

// ---------------- launch ----------------------------------------------------

extern "C" void kernel_launch(void* const* d_in, const int* in_sizes, int n_in,
                              void* d_out, int out_size, void* d_ws, size_t ws_size,
                              hipStream_t stream) {
    const float* x    = (const float*)d_in[0];
    const int*   esrc = (const int*)d_in[1];
    const int*   edst = (const int*)d_in[2];
    const float* ew   = (const float*)d_in[3];
    const float* Wm[4] = {(const float*)d_in[4], (const float*)d_in[6],
                          (const float*)d_in[8], (const float*)d_in[10]};
    const float* bm[4] = {(const float*)d_in[5], (const float*)d_in[7],
                          (const float*)d_in[9], (const float*)d_in[11]};
    const int NFEAT = 512;
    const int n_nodes = in_sizes[0] / NFEAT;
    const int n_edges = in_sizes[1];
    float* out = (float*)d_out;

    // --- workspace carve (256B aligned bump allocator) ---
    char* wsp = (char*)d_ws;
    size_t off = 0;
    auto alloc = [&](size_t bytes) -> void* {
        void* p = wsp + off;
        off += (bytes + 255) & ~(size_t)255;
        return p;
    };
    float* S       = (float*)alloc((size_t)n_nodes * 256 * sizeof(float)); // support
    float* G       = (float*)alloc((size_t)n_nodes * 256 * sizeof(float)); // aggregated h
    int*   counts  = (int*)alloc((size_t)n_nodes * sizeof(int));
    int*   row_ptr = (int*)alloc(((size_t)n_nodes + 1) * sizeof(int));
    int*   row_cur = (int*)alloc((size_t)n_nodes * sizeof(int));
    int*   bsum    = (int*)alloc(1024 * sizeof(int));
    int*   boff    = (int*)alloc(1024 * sizeof(int));
    int*   src_s   = (int*)alloc((size_t)n_edges * sizeof(int));
    float* ew_s    = (float*)alloc((size_t)n_edges * sizeof(float));
    (void)ws_size;

    // --- CSR build (once; reused by all 4 layers) ---
    hipMemsetAsync(counts, 0, (size_t)n_nodes * sizeof(int), stream);
    hist_kernel<<<(n_edges + 255) / 256, 256, 0, stream>>>(edst, n_edges, counts);
    int nb = (n_nodes + 1023) / 1024;
    scan1_kernel<<<nb, 1024, 0, stream>>>(counts, n_nodes, row_ptr, bsum);
    scan2_kernel<<<1, 1024, 0, stream>>>(bsum, nb, boff);
    scan3_kernel<<<(n_nodes + 255) / 256, 256, 0, stream>>>(row_ptr, boff, n_nodes,
                                                            n_edges, row_cur);
    scatter_kernel<<<(n_edges + 255) / 256, 256, 0, stream>>>(esrc, edst, ew, n_edges,
                                                              row_cur, src_s, ew_s);

    // --- layers ---
    auto gemm = [&](const float* A, const float* W, float* C, int K, int N) {
        dim3 grid((N + BN - 1) / BN, (n_nodes + BM - 1) / BM);
        gemm_kernel<<<grid, 256, 0, stream>>>(A, W, C, n_nodes, K, N);
    };
    int spmm_blocks = (n_nodes + 3) / 4;

    // L1: 512 -> 256
    gemm(x, Wm[0], S, 512, 256);
    spmm_bias_relu<256, 4><<<spmm_blocks, 256, 0, stream>>>(row_ptr, src_s, ew_s, S,
                                                            bm[0], G, n_nodes);
    // L2: 256 -> 128
    gemm(G, Wm[1], S, 256, 128);
    spmm_bias_relu<128, 2><<<spmm_blocks, 256, 0, stream>>>(row_ptr, src_s, ew_s, S,
                                                            bm[1], G, n_nodes);
    // L3: 128 -> 64
    gemm(G, Wm[2], S, 128, 64);
    spmm_bias_relu<64, 1><<<spmm_blocks, 256, 0, stream>>>(row_ptr, src_s, ew_s, S,
                                                           bm[2], G, n_nodes);
    // L4: 64 -> 40
    gemm(G, Wm[3], S, 64, 40);
    spmm_bias_relu<40, 1><<<spmm_blocks, 256, 0, stream>>>(row_ptr, src_s, ew_s, S,
                                                           bm[3], G, n_nodes);

    // final log_softmax
    logsoftmax40_kernel<<<spmm_blocks, 256, 0, stream>>>(G, out, n_nodes);
}

// Round 2
// 1903.493 us; speedup vs baseline: 1.3646x; 1.3646x over previous
//
#include <hip/hip_runtime.h>
#include <hip/hip_bf16.h>
#include <math.h>
#include <stdint.h>

// ---------------------------------------------------------------------------
// GCN 4-layer, bf16 datapath:
//   h = relu( A_w @ (h @ W) + b ) x4, then log_softmax (fp32 out).
//   - dst-CSR built once (histogram/scan/scatter)
//   - GEMM: bf16 MFMA 16x16x32, tile 128x64, BK=64, global_load_lds staging,
//     W pre-transposed to [N][K] bf16 (L4 zero-padded N 40->64)
//   - SpMM: one wave/dst node, bf16 gathers, fp32 accum, fused bias+relu
// ---------------------------------------------------------------------------

#define WAVE 64
typedef __attribute__((ext_vector_type(8))) short short8;
typedef __attribute__((ext_vector_type(4))) float floatx4;

__device__ __forceinline__ void async_copy16(const void* g, void* l) {
    __builtin_amdgcn_global_load_lds(
        (const __attribute__((address_space(1))) void*)g,
        (__attribute__((address_space(3))) void*)l, 16, 0, 0);
}
__device__ __forceinline__ float bf2f(unsigned short u) {
    union { unsigned int i; float f; } x; x.i = ((unsigned int)u) << 16; return x.f;
}

// ---------------- setup conversions ----------------

__global__ __launch_bounds__(256) void convert_x_kernel(const float* __restrict__ in,
                                                        __hip_bfloat16* __restrict__ out,
                                                        long n4) {
    long i = ((long)blockIdx.x * 256 + threadIdx.x);
    if (i >= n4) return;
    const float4 v = *(const float4*)(in + i * 4);
    __hip_bfloat16* o = out + i * 4;
    o[0] = __float2bfloat16(v.x); o[1] = __float2bfloat16(v.y);
    o[2] = __float2bfloat16(v.z); o[3] = __float2bfloat16(v.w);
}

// W [K][N] fp32 -> Wt [Npad][K] bf16 (rows >= N zeroed)
__global__ __launch_bounds__(256) void transpose_w_kernel(const float* __restrict__ W,
                                                          __hip_bfloat16* __restrict__ Wt,
                                                          int K, int N, int Npad) {
    int idx = blockIdx.x * 256 + threadIdx.x;
    if (idx >= Npad * K) return;
    int n = idx / K, k = idx - n * K;
    float v = (n < N) ? W[(size_t)k * N + n] : 0.f;
    Wt[idx] = __float2bfloat16(v);
}

__global__ void pad_bias_kernel(const float* __restrict__ b, float* __restrict__ bp,
                                int n, int npad) {
    int i = threadIdx.x;
    if (i < npad) bp[i] = (i < n) ? b[i] : 0.f;
}

// ---------------- CSR build ----------------

__global__ __launch_bounds__(256) void hist_kernel(const int* __restrict__ dst,
                                                   int nE, int* __restrict__ counts) {
    int i = blockIdx.x * 256 + threadIdx.x;
    if (i < nE) atomicAdd(&counts[dst[i]], 1);
}

__global__ __launch_bounds__(1024) void scan1_kernel(const int* __restrict__ counts,
                                                     int n, int* __restrict__ partial,
                                                     int* __restrict__ bsum) {
    __shared__ int sm[1024];
    int tid = threadIdx.x;
    int i = blockIdx.x * 1024 + tid;
    int x = (i < n) ? counts[i] : 0;
    sm[tid] = x;
    __syncthreads();
    for (int off = 1; off < 1024; off <<= 1) {
        int add = 0;
        if (tid >= off) add = sm[tid - off];
        __syncthreads();
        if (tid >= off) sm[tid] += add;
        __syncthreads();
    }
    int incl = sm[tid];
    if (i < n) partial[i] = incl - x;
    if (tid == 1023) bsum[blockIdx.x] = incl;
}

__global__ __launch_bounds__(1024) void scan2_kernel(const int* __restrict__ bsum,
                                                     int nb, int* __restrict__ boff) {
    __shared__ int sm[1024];
    int tid = threadIdx.x;
    int x = (tid < nb) ? bsum[tid] : 0;
    sm[tid] = x;
    __syncthreads();
    for (int off = 1; off < 1024; off <<= 1) {
        int add = 0;
        if (tid >= off) add = sm[tid - off];
        __syncthreads();
        if (tid >= off) sm[tid] += add;
        __syncthreads();
    }
    if (tid < nb) boff[tid] = sm[tid] - x;
}

__global__ __launch_bounds__(256) void scan3_kernel(int* __restrict__ row_ptr,
                                                    const int* __restrict__ boff,
                                                    int n, int nE,
                                                    int* __restrict__ row_cur) {
    int i = blockIdx.x * 256 + threadIdx.x;
    if (i < n) {
        int v = row_ptr[i] + boff[i >> 10];
        row_ptr[i] = v;
        row_cur[i] = v;
    }
    if (i == 0) row_ptr[n] = nE;
}

__global__ __launch_bounds__(256) void scatter_kernel(const int* __restrict__ src,
                                                      const int* __restrict__ dst,
                                                      const float* __restrict__ ew,
                                                      int nE,
                                                      int* __restrict__ row_cur,
                                                      int* __restrict__ src_s,
                                                      float* __restrict__ ew_s) {
    int i = blockIdx.x * 256 + threadIdx.x;
    if (i < nE) {
        int d = dst[i];
        int pos = atomicAdd(&row_cur[d], 1);
        src_s[pos] = src[i];
        ew_s[pos] = ew[i];
    }
}

// ---------------- bf16 MFMA GEMM: C[M,Npitch] = A[M,K] @ Wt[Npitch,K]^T -----
// tile 128x64, BK=64, 4 waves: wave (wy,wx) owns rows wy*64..+64, cols wx*32..+32

__global__ __launch_bounds__(256) void gemm_bf16(const __hip_bfloat16* __restrict__ A,
                                                 const __hip_bfloat16* __restrict__ Wt,
                                                 __hip_bfloat16* __restrict__ C,
                                                 int M, int K, int Npitch) {
    __shared__ __align__(16) __hip_bfloat16 sA[128 * 64];  // [row][k], 128B rows
    __shared__ __align__(16) __hip_bfloat16 sB[64 * 64];   // [n][k],   128B rows
    const int t = threadIdx.x;
    const int lane = t & 63;
    const int w = t >> 6;
    const int wy = w >> 1, wx = w & 1;
    const int quad = lane >> 4;
    const int l16 = lane & 15;
    const int row0 = blockIdx.y * 128;
    const int col0 = blockIdx.x * 64;

    floatx4 acc[4][2];
#pragma unroll
    for (int mt = 0; mt < 4; mt++)
#pragma unroll
        for (int nt = 0; nt < 2; nt++) acc[mt][nt] = 0;

    const int arow = t >> 3;           // 0..31 within round
    const int koff = (t & 7) * 8;      // k element offset of this thread's 16B

    for (int k0 = 0; k0 < K; k0 += 64) {
        // stage A: 128 rows x 64 k bf16 = 16 KB, 4 rounds of 256x16B
#pragma unroll
        for (int r = 0; r < 4; r++) {
            int gm = row0 + r * 32 + arow;
            int gmc = (gm < M) ? gm : 0;
            async_copy16(A + (size_t)gmc * K + k0 + koff,
                         (char*)sA + r * 4096 + t * 16);
        }
        // stage B: 64 n-rows x 64 k bf16 = 8 KB, 2 rounds
#pragma unroll
        for (int r = 0; r < 2; r++) {
            int n = r * 32 + arow;
            async_copy16(Wt + (size_t)(col0 + n) * K + k0 + koff,
                         (char*)sB + r * 4096 + t * 16);
        }
        __syncthreads();

        short8 af[4][2], bfr[2][2];
#pragma unroll
        for (int mt = 0; mt < 4; mt++)
#pragma unroll
            for (int kk = 0; kk < 2; kk++)
                af[mt][kk] = *(const short8*)((const char*)sA +
                             (wy * 64 + mt * 16 + l16) * 128 + kk * 64 + quad * 16);
#pragma unroll
        for (int nt = 0; nt < 2; nt++)
#pragma unroll
            for (int kk = 0; kk < 2; kk++)
                bfr[nt][kk] = *(const short8*)((const char*)sB +
                              (wx * 32 + nt * 16 + l16) * 128 + kk * 64 + quad * 16);
#pragma unroll
        for (int kk = 0; kk < 2; kk++)
#pragma unroll
            for (int mt = 0; mt < 4; mt++)
#pragma unroll
                for (int nt = 0; nt < 2; nt++)
                    acc[mt][nt] = __builtin_amdgcn_mfma_f32_16x16x32_bf16(
                        af[mt][kk], bfr[nt][kk], acc[mt][nt], 0, 0, 0);
        __syncthreads();
    }

    // epilogue: D col = lane&15 (B's n), row = quad*4+reg (A's m)
#pragma unroll
    for (int mt = 0; mt < 4; mt++) {
#pragma unroll
        for (int nt = 0; nt < 2; nt++) {
            int gn = col0 + wx * 32 + nt * 16 + l16;
            int gmb = row0 + wy * 64 + mt * 16 + quad * 4;
#pragma unroll
            for (int r = 0; r < 4; r++) {
                int gm = gmb + r;
                if (gm < M)
                    C[(size_t)gm * Npitch + gn] = __float2bfloat16(acc[mt][nt][r]);
            }
        }
    }
}

// ---------------- SpMM (CSR by dst) + bias + relu, bf16 gathers -------------

__device__ __forceinline__ void store_val(__hip_bfloat16* p, float v) {
    *p = __float2bfloat16(v);
}
__device__ __forceinline__ void store_val(float* p, float v) { *p = v; }

template <int D, int VEC, typename OT>
__global__ __launch_bounds__(256) void spmm_bias_relu(const int* __restrict__ row_ptr,
                                                      const int* __restrict__ src_s,
                                                      const float* __restrict__ ew_s,
                                                      const __hip_bfloat16* __restrict__ support,
                                                      const float* __restrict__ bias,
                                                      OT* __restrict__ out,
                                                      int n_nodes) {
    int node = blockIdx.x * (256 / WAVE) + (threadIdx.x >> 6);
    int lane = threadIdx.x & 63;
    if (node >= n_nodes) return;
    int beg = row_ptr[node];
    int end = row_ptr[node + 1];
    int col = lane * VEC;
    if (col >= D) return;

    float acc[VEC];
#pragma unroll
    for (int i = 0; i < VEC; i++) acc[i] = 0.f;

    const unsigned short* sup = (const unsigned short*)support;
    for (int e = beg; e < end; e++) {
        int s = src_s[e];
        float wgt = ew_s[e];
        const unsigned short* p = sup + (size_t)s * D + col;
        if (VEC == 4) {
            ushort4 v = *(const ushort4*)p;
            acc[0] += bf2f(v.x) * wgt; acc[1] += bf2f(v.y) * wgt;
            acc[2] += bf2f(v.z) * wgt; acc[3] += bf2f(v.w) * wgt;
        } else if (VEC == 2) {
            ushort2 v = *(const ushort2*)p;
            acc[0] += bf2f(v.x) * wgt; acc[1] += bf2f(v.y) * wgt;
        } else {
            acc[0] += bf2f(*p) * wgt;
        }
    }
#pragma unroll
    for (int i = 0; i < VEC; i++) {
        float r = acc[i] + bias[col + i];
        store_val(&out[(size_t)node * D + col + i], r > 0.f ? r : 0.f);
    }
}

// ---------------- log_softmax over 40 classes (input pitch 64, fp32) --------

__global__ __launch_bounds__(256) void logsoftmax40_kernel(const float* __restrict__ h,
                                                           float* __restrict__ out,
                                                           int n_nodes) {
    int row = blockIdx.x * (256 / WAVE) + (threadIdx.x >> 6);
    int lane = threadIdx.x & 63;
    if (row >= n_nodes) return;
    float v = (lane < 40) ? h[(size_t)row * 64 + lane] : -INFINITY;
    float m = v;
#pragma unroll
    for (int off = 32; off; off >>= 1) m = fmaxf(m, __shfl_xor(m, off));
    float e = (lane < 40) ? __expf(v - m) : 0.f;
    float s = e;
#pragma unroll
    for (int off = 32; off; off >>= 1) s += __shfl_xor(s, off);
    if (lane < 40) out[(size_t)row * 40 + lane] = v - m - __logf(s);
}

// ---------------- launch ----------------------------------------------------

extern "C" void kernel_launch(void* const* d_in, const int* in_sizes, int n_in,
                              void* d_out, int out_size, void* d_ws, size_t ws_size,
                              hipStream_t stream) {
    const float* x    = (const float*)d_in[0];
    const int*   esrc = (const int*)d_in[1];
    const int*   edst = (const int*)d_in[2];
    const float* ew   = (const float*)d_in[3];
    const float* Wm[4] = {(const float*)d_in[4], (const float*)d_in[6],
                          (const float*)d_in[8], (const float*)d_in[10]};
    const float* bm[4] = {(const float*)d_in[5], (const float*)d_in[7],
                          (const float*)d_in[9], (const float*)d_in[11]};
    const int NFEAT = 512;
    const int n_nodes = in_sizes[0] / NFEAT;
    const int n_edges = in_sizes[1];
    float* out = (float*)d_out;

    // --- workspace carve ---
    char* wsp = (char*)d_ws;
    size_t off = 0;
    auto alloc = [&](size_t bytes) -> void* {
        void* p = wsp + off;
        off += (bytes + 255) & ~(size_t)255;
        return p;
    };
    __hip_bfloat16* Xb = (__hip_bfloat16*)alloc((size_t)n_nodes * 512 * sizeof(__hip_bfloat16));
    __hip_bfloat16* Sb = (__hip_bfloat16*)alloc((size_t)n_nodes * 256 * sizeof(__hip_bfloat16));
    __hip_bfloat16* Hb = (__hip_bfloat16*)alloc((size_t)n_nodes * 256 * sizeof(__hip_bfloat16));
    __hip_bfloat16* Wt1 = (__hip_bfloat16*)alloc(256 * 512 * sizeof(__hip_bfloat16));
    __hip_bfloat16* Wt2 = (__hip_bfloat16*)alloc(128 * 256 * sizeof(__hip_bfloat16));
    __hip_bfloat16* Wt3 = (__hip_bfloat16*)alloc(64 * 128 * sizeof(__hip_bfloat16));
    __hip_bfloat16* Wt4 = (__hip_bfloat16*)alloc(64 * 64 * sizeof(__hip_bfloat16));
    float* b4p     = (float*)alloc(64 * sizeof(float));
    int*   counts  = (int*)alloc((size_t)n_nodes * sizeof(int));
    int*   row_ptr = (int*)alloc(((size_t)n_nodes + 1) * sizeof(int));
    int*   row_cur = (int*)alloc((size_t)n_nodes * sizeof(int));
    int*   bsum    = (int*)alloc(1024 * sizeof(int));
    int*   boff    = (int*)alloc(1024 * sizeof(int));
    int*   src_s   = (int*)alloc((size_t)n_edges * sizeof(int));
    float* ew_s    = (float*)alloc((size_t)n_edges * sizeof(float));
    // G4 (L4 fp32 output, pitch 64) aliases Xb — Xb is dead after the L1 GEMM.
    float* G4 = (float*)Xb;
    (void)ws_size;

    // --- conversions ---
    long n4 = (long)n_nodes * 512 / 4;
    convert_x_kernel<<<(int)((n4 + 255) / 256), 256, 0, stream>>>(x, Xb, n4);
    transpose_w_kernel<<<(256 * 512 + 255) / 256, 256, 0, stream>>>(Wm[0], Wt1, 512, 256, 256);
    transpose_w_kernel<<<(128 * 256 + 255) / 256, 256, 0, stream>>>(Wm[1], Wt2, 256, 128, 128);
    transpose_w_kernel<<<(64 * 128 + 255) / 256, 256, 0, stream>>>(Wm[2], Wt3, 128, 64, 64);
    transpose_w_kernel<<<(64 * 64 + 255) / 256, 256, 0, stream>>>(Wm[3], Wt4, 64, 40, 64);
    pad_bias_kernel<<<1, 64, 0, stream>>>(bm[3], b4p, 40, 64);

    // --- CSR build ---
    hipMemsetAsync(counts, 0, (size_t)n_nodes * sizeof(int), stream);
    hist_kernel<<<(n_edges + 255) / 256, 256, 0, stream>>>(edst, n_edges, counts);
    int nb = (n_nodes + 1023) / 1024;
    scan1_kernel<<<nb, 1024, 0, stream>>>(counts, n_nodes, row_ptr, bsum);
    scan2_kernel<<<1, 1024, 0, stream>>>(bsum, nb, boff);
    scan3_kernel<<<(n_nodes + 255) / 256, 256, 0, stream>>>(row_ptr, boff, n_nodes,
                                                            n_edges, row_cur);
    scatter_kernel<<<(n_edges + 255) / 256, 256, 0, stream>>>(esrc, edst, ew, n_edges,
                                                              row_cur, src_s, ew_s);

    // --- layers ---
    auto gemm = [&](const __hip_bfloat16* A, const __hip_bfloat16* Wt,
                    __hip_bfloat16* C, int K, int Npitch) {
        dim3 grid(Npitch / 64, (n_nodes + 127) / 128);
        gemm_bf16<<<grid, 256, 0, stream>>>(A, Wt, C, n_nodes, K, Npitch);
    };
    int spmm_blocks = (n_nodes + 3) / 4;

    // L1: 512 -> 256
    gemm(Xb, Wt1, Sb, 512, 256);
    spmm_bias_relu<256, 4, __hip_bfloat16><<<spmm_blocks, 256, 0, stream>>>(
        row_ptr, src_s, ew_s, Sb, bm[0], Hb, n_nodes);
    // L2: 256 -> 128
    gemm(Hb, Wt2, Sb, 256, 128);
    spmm_bias_relu<128, 2, __hip_bfloat16><<<spmm_blocks, 256, 0, stream>>>(
        row_ptr, src_s, ew_s, Sb, bm[1], Hb, n_nodes);
    // L3: 128 -> 64
    gemm(Hb, Wt3, Sb, 128, 64);
    spmm_bias_relu<64, 1, __hip_bfloat16><<<spmm_blocks, 256, 0, stream>>>(
        row_ptr, src_s, ew_s, Sb, bm[2], Hb, n_nodes);
    // L4: 64 -> 40 (padded to 64; padded support/bias are zero)
    gemm(Hb, Wt4, Sb, 64, 64);
    spmm_bias_relu<64, 1, float><<<spmm_blocks, 256, 0, stream>>>(
        row_ptr, src_s, ew_s, Sb, b4p, G4, n_nodes);

    // final log_softmax (reads pitch-64 fp32, writes [n,40] fp32)
    logsoftmax40_kernel<<<spmm_blocks, 256, 0, stream>>>(G4, out, n_nodes);
}

// Round 3
// 1234.306 us; speedup vs baseline: 2.1045x; 1.5422x over previous
//
#include <hip/hip_runtime.h>
#include <hip/hip_bf16.h>
#include <math.h>
#include <stdint.h>

// ---------------------------------------------------------------------------
// GCN 4-layer, bf16 datapath:
//   h = relu( A_w @ (h @ W) + b ) x4, then log_softmax (fp32 out).
//   - dst-CSR built once (histogram/scan/scatter)
//   - GEMM: bf16 MFMA 16x16x32, tile 128x64, BK=64, global_load_lds staging
//   - SpMM: one wave/dst node, edge loop UNROLLED (U gathers in flight),
//     scalarized index loads, bf16 gathers, fp32 accum, fused bias+relu
// ---------------------------------------------------------------------------

#define WAVE 64
typedef __attribute__((ext_vector_type(8))) short short8;
typedef __attribute__((ext_vector_type(4))) float floatx4;

__device__ __forceinline__ void async_copy16(const void* g, void* l) {
    __builtin_amdgcn_global_load_lds(
        (const __attribute__((address_space(1))) void*)g,
        (__attribute__((address_space(3))) void*)l, 16, 0, 0);
}
__device__ __forceinline__ float bf2f(unsigned short u) {
    union { unsigned int i; float f; } x; x.i = ((unsigned int)u) << 16; return x.f;
}

// ---------------- setup conversions ----------------

__global__ __launch_bounds__(256) void convert_x_kernel(const float* __restrict__ in,
                                                        __hip_bfloat16* __restrict__ out,
                                                        long n4) {
    long i = ((long)blockIdx.x * 256 + threadIdx.x);
    if (i >= n4) return;
    const float4 v = *(const float4*)(in + i * 4);
    __hip_bfloat16* o = out + i * 4;
    o[0] = __float2bfloat16(v.x); o[1] = __float2bfloat16(v.y);
    o[2] = __float2bfloat16(v.z); o[3] = __float2bfloat16(v.w);
}

// W [K][N] fp32 -> Wt [Npad][K] bf16 (rows >= N zeroed)
__global__ __launch_bounds__(256) void transpose_w_kernel(const float* __restrict__ W,
                                                          __hip_bfloat16* __restrict__ Wt,
                                                          int K, int N, int Npad) {
    int idx = blockIdx.x * 256 + threadIdx.x;
    if (idx >= Npad * K) return;
    int n = idx / K, k = idx - n * K;
    float v = (n < N) ? W[(size_t)k * N + n] : 0.f;
    Wt[idx] = __float2bfloat16(v);
}

__global__ void pad_bias_kernel(const float* __restrict__ b, float* __restrict__ bp,
                                int n, int npad) {
    int i = threadIdx.x;
    if (i < npad) bp[i] = (i < n) ? b[i] : 0.f;
}

// ---------------- CSR build ----------------

__global__ __launch_bounds__(256) void hist_kernel(const int* __restrict__ dst,
                                                   int nE, int* __restrict__ counts) {
    int i = blockIdx.x * 256 + threadIdx.x;
    if (i < nE) atomicAdd(&counts[dst[i]], 1);
}

__global__ __launch_bounds__(1024) void scan1_kernel(const int* __restrict__ counts,
                                                     int n, int* __restrict__ partial,
                                                     int* __restrict__ bsum) {
    __shared__ int sm[1024];
    int tid = threadIdx.x;
    int i = blockIdx.x * 1024 + tid;
    int x = (i < n) ? counts[i] : 0;
    sm[tid] = x;
    __syncthreads();
    for (int off = 1; off < 1024; off <<= 1) {
        int add = 0;
        if (tid >= off) add = sm[tid - off];
        __syncthreads();
        if (tid >= off) sm[tid] += add;
        __syncthreads();
    }
    int incl = sm[tid];
    if (i < n) partial[i] = incl - x;
    if (tid == 1023) bsum[blockIdx.x] = incl;
}

__global__ __launch_bounds__(1024) void scan2_kernel(const int* __restrict__ bsum,
                                                     int nb, int* __restrict__ boff) {
    __shared__ int sm[1024];
    int tid = threadIdx.x;
    int x = (tid < nb) ? bsum[tid] : 0;
    sm[tid] = x;
    __syncthreads();
    for (int off = 1; off < 1024; off <<= 1) {
        int add = 0;
        if (tid >= off) add = sm[tid - off];
        __syncthreads();
        if (tid >= off) sm[tid] += add;
        __syncthreads();
    }
    if (tid < nb) boff[tid] = sm[tid] - x;
}

__global__ __launch_bounds__(256) void scan3_kernel(int* __restrict__ row_ptr,
                                                    const int* __restrict__ boff,
                                                    int n, int nE,
                                                    int* __restrict__ row_cur) {
    int i = blockIdx.x * 256 + threadIdx.x;
    if (i < n) {
        int v = row_ptr[i] + boff[i >> 10];
        row_ptr[i] = v;
        row_cur[i] = v;
    }
    if (i == 0) row_ptr[n] = nE;
}

__global__ __launch_bounds__(256) void scatter_kernel(const int* __restrict__ src,
                                                      const int* __restrict__ dst,
                                                      const float* __restrict__ ew,
                                                      int nE,
                                                      int* __restrict__ row_cur,
                                                      int* __restrict__ src_s,
                                                      float* __restrict__ ew_s) {
    int i = blockIdx.x * 256 + threadIdx.x;
    if (i < nE) {
        int d = dst[i];
        int pos = atomicAdd(&row_cur[d], 1);
        src_s[pos] = src[i];
        ew_s[pos] = ew[i];
    }
}

// ---------------- bf16 MFMA GEMM: C[M,Npitch] = A[M,K] @ Wt[Npitch,K]^T -----

__global__ __launch_bounds__(256) void gemm_bf16(const __hip_bfloat16* __restrict__ A,
                                                 const __hip_bfloat16* __restrict__ Wt,
                                                 __hip_bfloat16* __restrict__ C,
                                                 int M, int K, int Npitch) {
    __shared__ __align__(16) __hip_bfloat16 sA[128 * 64];  // [row][k], 128B rows
    __shared__ __align__(16) __hip_bfloat16 sB[64 * 64];   // [n][k],   128B rows
    const int t = threadIdx.x;
    const int lane = t & 63;
    const int w = t >> 6;
    const int wy = w >> 1, wx = w & 1;
    const int quad = lane >> 4;
    const int l16 = lane & 15;
    const int row0 = blockIdx.y * 128;
    const int col0 = blockIdx.x * 64;

    floatx4 acc[4][2];
#pragma unroll
    for (int mt = 0; mt < 4; mt++)
#pragma unroll
        for (int nt = 0; nt < 2; nt++) acc[mt][nt] = 0;

    const int arow = t >> 3;           // 0..31 within round
    const int koff = (t & 7) * 8;      // k element offset of this thread's 16B

    for (int k0 = 0; k0 < K; k0 += 64) {
#pragma unroll
        for (int r = 0; r < 4; r++) {
            int gm = row0 + r * 32 + arow;
            int gmc = (gm < M) ? gm : 0;
            async_copy16(A + (size_t)gmc * K + k0 + koff,
                         (char*)sA + r * 4096 + t * 16);
        }
#pragma unroll
        for (int r = 0; r < 2; r++) {
            int n = r * 32 + arow;
            async_copy16(Wt + (size_t)(col0 + n) * K + k0 + koff,
                         (char*)sB + r * 4096 + t * 16);
        }
        __syncthreads();

        short8 af[4][2], bfr[2][2];
#pragma unroll
        for (int mt = 0; mt < 4; mt++)
#pragma unroll
            for (int kk = 0; kk < 2; kk++)
                af[mt][kk] = *(const short8*)((const char*)sA +
                             (wy * 64 + mt * 16 + l16) * 128 + kk * 64 + quad * 16);
#pragma unroll
        for (int nt = 0; nt < 2; nt++)
#pragma unroll
            for (int kk = 0; kk < 2; kk++)
                bfr[nt][kk] = *(const short8*)((const char*)sB +
                              (wx * 32 + nt * 16 + l16) * 128 + kk * 64 + quad * 16);
#pragma unroll
        for (int kk = 0; kk < 2; kk++)
#pragma unroll
            for (int mt = 0; mt < 4; mt++)
#pragma unroll
                for (int nt = 0; nt < 2; nt++)
                    acc[mt][nt] = __builtin_amdgcn_mfma_f32_16x16x32_bf16(
                        af[mt][kk], bfr[nt][kk], acc[mt][nt], 0, 0, 0);
        __syncthreads();
    }

#pragma unroll
    for (int mt = 0; mt < 4; mt++) {
#pragma unroll
        for (int nt = 0; nt < 2; nt++) {
            int gn = col0 + wx * 32 + nt * 16 + l16;
            int gmb = row0 + wy * 64 + mt * 16 + quad * 4;
#pragma unroll
            for (int r = 0; r < 4; r++) {
                int gm = gmb + r;
                if (gm < M)
                    C[(size_t)gm * Npitch + gn] = __float2bfloat16(acc[mt][nt][r]);
            }
        }
    }
}

// ---------------- SpMM (CSR by dst) + bias + relu, bf16 gathers -------------
// One wave per dst node; edge loop unrolled by U so U gathers are in flight.
// Node id scalarized so index/weight loads use the scalar (SMEM) pipe.

__device__ __forceinline__ void store_val(__hip_bfloat16* p, float v) {
    *p = __float2bfloat16(v);
}
__device__ __forceinline__ void store_val(float* p, float v) { *p = v; }

template <int D, int VEC, int U, typename OT>
__global__ __launch_bounds__(256) void spmm_bias_relu(const int* __restrict__ row_ptr,
                                                      const int* __restrict__ src_s,
                                                      const float* __restrict__ ew_s,
                                                      const __hip_bfloat16* __restrict__ support,
                                                      const float* __restrict__ bias,
                                                      OT* __restrict__ out,
                                                      int n_nodes) {
    int node = blockIdx.x * (256 / WAVE) + (threadIdx.x >> 6);
    int lane = threadIdx.x & 63;
    if (node >= n_nodes) return;
    node = __builtin_amdgcn_readfirstlane(node);   // wave-uniform -> scalar loads
    int beg = row_ptr[node];
    int end = row_ptr[node + 1];
    int col = lane * VEC;
    if (col >= D) return;

    float acc[VEC];
#pragma unroll
    for (int i = 0; i < VEC; i++) acc[i] = 0.f;

    const unsigned short* sup = (const unsigned short*)support;
    int e = beg;
    // main unrolled loop: U independent gathers in flight
    for (; e + U <= end; e += U) {
        int s[U]; float wgt[U];
#pragma unroll
        for (int u = 0; u < U; u++) { s[u] = src_s[e + u]; wgt[u] = ew_s[e + u]; }
        if (VEC == 4) {
            ushort4 v[U];
#pragma unroll
            for (int u = 0; u < U; u++)
                v[u] = *(const ushort4*)(sup + (size_t)s[u] * D + col);
#pragma unroll
            for (int u = 0; u < U; u++) {
                acc[0] += bf2f(v[u].x) * wgt[u]; acc[1] += bf2f(v[u].y) * wgt[u];
                acc[2] += bf2f(v[u].z) * wgt[u]; acc[3] += bf2f(v[u].w) * wgt[u];
            }
        } else if (VEC == 2) {
            ushort2 v[U];
#pragma unroll
            for (int u = 0; u < U; u++)
                v[u] = *(const ushort2*)(sup + (size_t)s[u] * D + col);
#pragma unroll
            for (int u = 0; u < U; u++) {
                acc[0] += bf2f(v[u].x) * wgt[u]; acc[1] += bf2f(v[u].y) * wgt[u];
            }
        } else {
            unsigned short v[U];
#pragma unroll
            for (int u = 0; u < U; u++) v[u] = sup[(size_t)s[u] * D + col];
#pragma unroll
            for (int u = 0; u < U; u++) acc[0] += bf2f(v[u]) * wgt[u];
        }
    }
    // remainder
    for (; e < end; e++) {
        int s = src_s[e];
        float wgt = ew_s[e];
        const unsigned short* p = sup + (size_t)s * D + col;
        if (VEC == 4) {
            ushort4 v = *(const ushort4*)p;
            acc[0] += bf2f(v.x) * wgt; acc[1] += bf2f(v.y) * wgt;
            acc[2] += bf2f(v.z) * wgt; acc[3] += bf2f(v.w) * wgt;
        } else if (VEC == 2) {
            ushort2 v = *(const ushort2*)p;
            acc[0] += bf2f(v.x) * wgt; acc[1] += bf2f(v.y) * wgt;
        } else {
            acc[0] += bf2f(*p) * wgt;
        }
    }
#pragma unroll
    for (int i = 0; i < VEC; i++) {
        float r = acc[i] + bias[col + i];
        store_val(&out[(size_t)node * D + col + i], r > 0.f ? r : 0.f);
    }
}

// ---------------- log_softmax over 40 classes (input pitch 64, fp32) --------

__global__ __launch_bounds__(256) void logsoftmax40_kernel(const float* __restrict__ h,
                                                           float* __restrict__ out,
                                                           int n_nodes) {
    int row = blockIdx.x * (256 / WAVE) + (threadIdx.x >> 6);
    int lane = threadIdx.x & 63;
    if (row >= n_nodes) return;
    float v = (lane < 40) ? h[(size_t)row * 64 + lane] : -INFINITY;
    float m = v;
#pragma unroll
    for (int off = 32; off; off >>= 1) m = fmaxf(m, __shfl_xor(m, off));
    float e = (lane < 40) ? __expf(v - m) : 0.f;
    float s = e;
#pragma unroll
    for (int off = 32; off; off >>= 1) s += __shfl_xor(s, off);
    if (lane < 40) out[(size_t)row * 40 + lane] = v - m - __logf(s);
}

// ---------------- launch ----------------------------------------------------

extern "C" void kernel_launch(void* const* d_in, const int* in_sizes, int n_in,
                              void* d_out, int out_size, void* d_ws, size_t ws_size,
                              hipStream_t stream) {
    const float* x    = (const float*)d_in[0];
    const int*   esrc = (const int*)d_in[1];
    const int*   edst = (const int*)d_in[2];
    const float* ew   = (const float*)d_in[3];
    const float* Wm[4] = {(const float*)d_in[4], (const float*)d_in[6],
                          (const float*)d_in[8], (const float*)d_in[10]};
    const float* bm[4] = {(const float*)d_in[5], (const float*)d_in[7],
                          (const float*)d_in[9], (const float*)d_in[11]};
    const int NFEAT = 512;
    const int n_nodes = in_sizes[0] / NFEAT;
    const int n_edges = in_sizes[1];
    float* out = (float*)d_out;

    // --- workspace carve ---
    char* wsp = (char*)d_ws;
    size_t off = 0;
    auto alloc = [&](size_t bytes) -> void* {
        void* p = wsp + off;
        off += (bytes + 255) & ~(size_t)255;
        return p;
    };
    __hip_bfloat16* Xb = (__hip_bfloat16*)alloc((size_t)n_nodes * 512 * sizeof(__hip_bfloat16));
    __hip_bfloat16* Sb = (__hip_bfloat16*)alloc((size_t)n_nodes * 256 * sizeof(__hip_bfloat16));
    __hip_bfloat16* Hb = (__hip_bfloat16*)alloc((size_t)n_nodes * 256 * sizeof(__hip_bfloat16));
    __hip_bfloat16* Wt1 = (__hip_bfloat16*)alloc(256 * 512 * sizeof(__hip_bfloat16));
    __hip_bfloat16* Wt2 = (__hip_bfloat16*)alloc(128 * 256 * sizeof(__hip_bfloat16));
    __hip_bfloat16* Wt3 = (__hip_bfloat16*)alloc(64 * 128 * sizeof(__hip_bfloat16));
    __hip_bfloat16* Wt4 = (__hip_bfloat16*)alloc(64 * 64 * sizeof(__hip_bfloat16));
    float* b4p     = (float*)alloc(64 * sizeof(float));
    int*   counts  = (int*)alloc((size_t)n_nodes * sizeof(int));
    int*   row_ptr = (int*)alloc(((size_t)n_nodes + 1) * sizeof(int));
    int*   row_cur = (int*)alloc((size_t)n_nodes * sizeof(int));
    int*   bsum    = (int*)alloc(1024 * sizeof(int));
    int*   boff    = (int*)alloc(1024 * sizeof(int));
    int*   src_s   = (int*)alloc((size_t)n_edges * sizeof(int));
    float* ew_s    = (float*)alloc((size_t)n_edges * sizeof(float));
    // G4 (L4 fp32 output, pitch 64) aliases Xb — Xb is dead after the L1 GEMM.
    float* G4 = (float*)Xb;
    (void)ws_size;

    // --- conversions ---
    long n4 = (long)n_nodes * 512 / 4;
    convert_x_kernel<<<(int)((n4 + 255) / 256), 256, 0, stream>>>(x, Xb, n4);
    transpose_w_kernel<<<(256 * 512 + 255) / 256, 256, 0, stream>>>(Wm[0], Wt1, 512, 256, 256);
    transpose_w_kernel<<<(128 * 256 + 255) / 256, 256, 0, stream>>>(Wm[1], Wt2, 256, 128, 128);
    transpose_w_kernel<<<(64 * 128 + 255) / 256, 256, 0, stream>>>(Wm[2], Wt3, 128, 64, 64);
    transpose_w_kernel<<<(64 * 64 + 255) / 256, 256, 0, stream>>>(Wm[3], Wt4, 64, 40, 64);
    pad_bias_kernel<<<1, 64, 0, stream>>>(bm[3], b4p, 40, 64);

    // --- CSR build ---
    hipMemsetAsync(counts, 0, (size_t)n_nodes * sizeof(int), stream);
    hist_kernel<<<(n_edges + 255) / 256, 256, 0, stream>>>(edst, n_edges, counts);
    int nb = (n_nodes + 1023) / 1024;
    scan1_kernel<<<nb, 1024, 0, stream>>>(counts, n_nodes, row_ptr, bsum);
    scan2_kernel<<<1, 1024, 0, stream>>>(bsum, nb, boff);
    scan3_kernel<<<(n_nodes + 255) / 256, 256, 0, stream>>>(row_ptr, boff, n_nodes,
                                                            n_edges, row_cur);
    scatter_kernel<<<(n_edges + 255) / 256, 256, 0, stream>>>(esrc, edst, ew, n_edges,
                                                              row_cur, src_s, ew_s);

    // --- layers ---
    auto gemm = [&](const __hip_bfloat16* A, const __hip_bfloat16* Wt,
                    __hip_bfloat16* C, int K, int Npitch) {
        dim3 grid(Npitch / 64, (n_nodes + 127) / 128);
        gemm_bf16<<<grid, 256, 0, stream>>>(A, Wt, C, n_nodes, K, Npitch);
    };
    int spmm_blocks = (n_nodes + 3) / 4;

    // L1: 512 -> 256
    gemm(Xb, Wt1, Sb, 512, 256);
    spmm_bias_relu<256, 4, 4, __hip_bfloat16><<<spmm_blocks, 256, 0, stream>>>(
        row_ptr, src_s, ew_s, Sb, bm[0], Hb, n_nodes);
    // L2: 256 -> 128
    gemm(Hb, Wt2, Sb, 256, 128);
    spmm_bias_relu<128, 2, 4, __hip_bfloat16><<<spmm_blocks, 256, 0, stream>>>(
        row_ptr, src_s, ew_s, Sb, bm[1], Hb, n_nodes);
    // L3: 128 -> 64
    gemm(Hb, Wt3, Sb, 128, 64);
    spmm_bias_relu<64, 1, 8, __hip_bfloat16><<<spmm_blocks, 256, 0, stream>>>(
        row_ptr, src_s, ew_s, Sb, bm[2], Hb, n_nodes);
    // L4: 64 -> 40 (padded to 64; padded support/bias are zero)
    gemm(Hb, Wt4, Sb, 64, 64);
    spmm_bias_relu<64, 1, 8, float><<<spmm_blocks, 256, 0, stream>>>(
        row_ptr, src_s, ew_s, Sb, b4p, G4, n_nodes);

    // final log_softmax (reads pitch-64 fp32, writes [n,40] fp32)
    logsoftmax40_kernel<<<spmm_blocks, 256, 0, stream>>>(G4, out, n_nodes);
}